// Round 4
// baseline (311.464 us; speedup 1.0000x reference)
//
#include <hip/hip_runtime.h>

// ContrastiveLoss: B=8192 rows, D=4096 fp32 features. Fully fused single kernel.
// One 256-thread block per row: each thread does 4+4 independent float4 loads
// (straight-line, max MLP), block-reduces dot/||a||^2/||b||^2, thread 0 computes
// the per-row loss. Last-finished block (device-scope counter) reduces all row
// losses in fixed order -> deterministic mean -> d_out[0].
//
// target arrives as int32 (JAX x32 default; harness passes integer -> const int*).

#define BLOCK 256
#define WAVE 64

__global__ __launch_bounds__(BLOCK) void contrastive_fused(
    const float* __restrict__ o1,
    const float* __restrict__ o2,
    const int* __restrict__ target,
    float* __restrict__ row_loss,
    unsigned int* __restrict__ done_ctr,
    float* __restrict__ out,
    int B, int D) {
    const int tid  = threadIdx.x;
    const int lane = tid & 63;
    const int wv   = tid >> 6;           // 0..3
    const int row  = blockIdx.x;

    const float4* __restrict__ p1 =
        reinterpret_cast<const float4*>(o1 + (size_t)row * D);
    const float4* __restrict__ p2 =
        reinterpret_cast<const float4*>(o2 + (size_t)row * D);
    const int nvec = D >> 2;             // 1024 for D=4096

    float dot, s1, s2;
    if (nvec == 1024) {
        // Straight-line: 8 independent 16B loads per thread, all in flight.
        float4 a0 = p1[tid];
        float4 a1 = p1[tid + 256];
        float4 a2 = p1[tid + 512];
        float4 a3 = p1[tid + 768];
        float4 b0 = p2[tid];
        float4 b1 = p2[tid + 256];
        float4 b2 = p2[tid + 512];
        float4 b3 = p2[tid + 768];

        float d0 = a0.x * b0.x + a0.y * b0.y + a0.z * b0.z + a0.w * b0.w;
        float d1 = a1.x * b1.x + a1.y * b1.y + a1.z * b1.z + a1.w * b1.w;
        float d2 = a2.x * b2.x + a2.y * b2.y + a2.z * b2.z + a2.w * b2.w;
        float d3 = a3.x * b3.x + a3.y * b3.y + a3.z * b3.z + a3.w * b3.w;

        float e0 = a0.x * a0.x + a0.y * a0.y + a0.z * a0.z + a0.w * a0.w;
        float e1 = a1.x * a1.x + a1.y * a1.y + a1.z * a1.z + a1.w * a1.w;
        float e2 = a2.x * a2.x + a2.y * a2.y + a2.z * a2.z + a2.w * a2.w;
        float e3 = a3.x * a3.x + a3.y * a3.y + a3.z * a3.z + a3.w * a3.w;

        float f0 = b0.x * b0.x + b0.y * b0.y + b0.z * b0.z + b0.w * b0.w;
        float f1 = b1.x * b1.x + b1.y * b1.y + b1.z * b1.z + b1.w * b1.w;
        float f2 = b2.x * b2.x + b2.y * b2.y + b2.z * b2.z + b2.w * b2.w;
        float f3 = b3.x * b3.x + b3.y * b3.y + b3.z * b3.z + b3.w * b3.w;

        dot = (d0 + d1) + (d2 + d3);
        s1  = (e0 + e1) + (e2 + e3);
        s2  = (f0 + f1) + (f2 + f3);
    } else {
        // Generic fallback.
        dot = 0.f; s1 = 0.f; s2 = 0.f;
        for (int i = tid; i < nvec; i += BLOCK) {
            float4 a = p1[i];
            float4 b = p2[i];
            dot += a.x * b.x + a.y * b.y + a.z * b.z + a.w * b.w;
            s1  += a.x * a.x + a.y * a.y + a.z * a.z + a.w * a.w;
            s2  += b.x * b.x + b.y * b.y + b.z * b.z + b.w * b.w;
        }
    }

    // Wave reduction (64 lanes).
    #pragma unroll
    for (int off = 32; off > 0; off >>= 1) {
        dot += __shfl_down(dot, off, WAVE);
        s1  += __shfl_down(s1,  off, WAVE);
        s2  += __shfl_down(s2,  off, WAVE);
    }

    __shared__ float sd[4], se[4], sf[4];
    __shared__ bool is_last;
    if (lane == 0) { sd[wv] = dot; se[wv] = s1; sf[wv] = s2; }
    __syncthreads();

    if (tid == 0) {
        float dt  = (sd[0] + sd[1]) + (sd[2] + sd[3]);
        float ss1 = (se[0] + se[1]) + (se[2] + se[3]);
        float ss2 = (sf[0] + sf[1]) + (sf[2] + sf[3]);

        float cosv = dt / (sqrtf(ss1) * sqrtf(ss2));
        float dist = 0.5f * (1.0f - cosv);
        int t = target[row];
        float loss;
        if (t != 0) {
            loss = 0.5f * dist;
        } else {
            float h = fmaxf(0.0f, 1.0f - sqrtf(dist + 1e-9f));
            loss = 0.5f * h * h;
        }
        row_loss[row] = loss;

        __threadfence();                        // release our row_loss store
        unsigned old = atomicAdd(done_ctr, 1u); // device-scope
        is_last = (old == (unsigned)(gridDim.x - 1));
    }
    __syncthreads();
    if (!is_last) return;

    // Last block: all other blocks' stores are device-visible (they fenced
    // before their atomicAdd). Acquire fence, then fixed-order reduction.
    __threadfence();
    const float4* __restrict__ rl = reinterpret_cast<const float4*>(row_loss);
    const int nv = B >> 2;                      // 2048
    float sum = 0.0f;
    for (int i = tid; i < nv; i += BLOCK) {
        float4 v = rl[i];
        sum += (v.x + v.y) + (v.z + v.w);
    }
    #pragma unroll
    for (int off = 32; off > 0; off >>= 1) sum += __shfl_down(sum, off, WAVE);

    __shared__ float ssum[4];
    if (lane == 0) ssum[wv] = sum;
    __syncthreads();
    if (tid == 0) {
        out[0] = ((ssum[0] + ssum[1]) + (ssum[2] + ssum[3])) / (float)B;
    }
}

extern "C" void kernel_launch(void* const* d_in, const int* in_sizes, int n_in,
                              void* d_out, int out_size, void* d_ws, size_t ws_size,
                              hipStream_t stream) {
    const float* o1 = (const float*)d_in[0];
    const float* o2 = (const float*)d_in[1];
    const int* tgt = (const int*)d_in[2];

    const int B = in_sizes[2];            // 8192
    const int D = in_sizes[0] / B;        // 4096

    float* row_loss = (float*)d_ws;                         // B floats
    unsigned int* done_ctr =
        (unsigned int*)((char*)d_ws + (size_t)B * sizeof(float));
    float* out = (float*)d_out;

    // Zero the completion counter each call (graph-capturable async memset).
    hipMemsetAsync(done_ctr, 0, sizeof(unsigned int), stream);

    contrastive_fused<<<B, BLOCK, 0, stream>>>(o1, o2, tgt, row_loss,
                                               done_ctr, out, B, D);
}

// Round 5
// 47.589 us; speedup vs baseline: 6.5448x; 6.5448x over previous
//
#include <hip/hip_runtime.h>

// ContrastiveLoss: B=8192 rows, D=4096 fp32 features. Two kernels (per-block
// device-scope sync was a 380us serial tail at this grid size -- see R4).
//
// Kernel 1: one 64-lane wave per row, FULLY unrolled: 16+16 float4 loads all
//   issued before any FMA (sched_barrier pin) -> max memory-level parallelism.
//   4 rows/block; block writes ONE partial (sum of its 4 row losses).
// Kernel 2: single block reduces 2048 partials in fixed order -> mean.
//
// target arrives as int32 (JAX x32 default; harness passes integer -> const int*).

#define WAVE 64
#define BLOCK 256
#define WAVES_PER_BLOCK (BLOCK / WAVE)

__global__ __launch_bounds__(BLOCK) void contrastive_row_loss(
    const float* __restrict__ o1,
    const float* __restrict__ o2,
    const int* __restrict__ target,
    float* __restrict__ block_partial,
    int B, int D) {
    const int wv   = threadIdx.x >> 6;      // 0..3
    const int lane = threadIdx.x & 63;
    const int row  = blockIdx.x * WAVES_PER_BLOCK + wv;

    float dot = 0.f, s1 = 0.f, s2 = 0.f;

    if (row < B) {
        const float4* __restrict__ p1 =
            reinterpret_cast<const float4*>(o1 + (size_t)row * D);
        const float4* __restrict__ p2 =
            reinterpret_cast<const float4*>(o2 + (size_t)row * D);
        const int nvec = D >> 2;            // 1024 for D=4096

        if (nvec == 1024) {
            // 16 float4 per input per lane, fully unrolled; all 32 loads
            // issued before any arithmetic (sched_barrier pin below).
            float4 a[16], b[16];
            #pragma unroll
            for (int k = 0; k < 16; ++k) a[k] = p1[lane + WAVE * k];
            #pragma unroll
            for (int k = 0; k < 16; ++k) b[k] = p2[lane + WAVE * k];
            __builtin_amdgcn_sched_barrier(0);  // no FMA hoisted above loads

            float d0 = 0.f, d1 = 0.f, d2 = 0.f, d3 = 0.f;
            float e0 = 0.f, e1 = 0.f, e2 = 0.f, e3 = 0.f;
            float f0 = 0.f, f1 = 0.f, f2 = 0.f, f3 = 0.f;
            #pragma unroll
            for (int k = 0; k < 16; k += 4) {
                d0 += a[k].x*b[k].x + a[k].y*b[k].y + a[k].z*b[k].z + a[k].w*b[k].w;
                e0 += a[k].x*a[k].x + a[k].y*a[k].y + a[k].z*a[k].z + a[k].w*a[k].w;
                f0 += b[k].x*b[k].x + b[k].y*b[k].y + b[k].z*b[k].z + b[k].w*b[k].w;

                d1 += a[k+1].x*b[k+1].x + a[k+1].y*b[k+1].y + a[k+1].z*b[k+1].z + a[k+1].w*b[k+1].w;
                e1 += a[k+1].x*a[k+1].x + a[k+1].y*a[k+1].y + a[k+1].z*a[k+1].z + a[k+1].w*a[k+1].w;
                f1 += b[k+1].x*b[k+1].x + b[k+1].y*b[k+1].y + b[k+1].z*b[k+1].z + b[k+1].w*b[k+1].w;

                d2 += a[k+2].x*b[k+2].x + a[k+2].y*b[k+2].y + a[k+2].z*b[k+2].z + a[k+2].w*b[k+2].w;
                e2 += a[k+2].x*a[k+2].x + a[k+2].y*a[k+2].y + a[k+2].z*a[k+2].z + a[k+2].w*a[k+2].w;
                f2 += b[k+2].x*b[k+2].x + b[k+2].y*b[k+2].y + b[k+2].z*b[k+2].z + b[k+2].w*b[k+2].w;

                d3 += a[k+3].x*b[k+3].x + a[k+3].y*b[k+3].y + a[k+3].z*b[k+3].z + a[k+3].w*b[k+3].w;
                e3 += a[k+3].x*a[k+3].x + a[k+3].y*a[k+3].y + a[k+3].z*a[k+3].z + a[k+3].w*a[k+3].w;
                f3 += b[k+3].x*b[k+3].x + b[k+3].y*b[k+3].y + b[k+3].z*b[k+3].z + b[k+3].w*b[k+3].w;
            }
            dot = (d0 + d1) + (d2 + d3);
            s1  = (e0 + e1) + (e2 + e3);
            s2  = (f0 + f1) + (f2 + f3);
        } else {
            for (int i = lane; i < nvec; i += WAVE) {
                float4 a = p1[i];
                float4 b = p2[i];
                dot += a.x*b.x + a.y*b.y + a.z*b.z + a.w*b.w;
                s1  += a.x*a.x + a.y*a.y + a.z*a.z + a.w*a.w;
                s2  += b.x*b.x + b.y*b.y + b.z*b.z + b.w*b.w;
            }
        }
    }

    // 64-lane wave reduction.
    #pragma unroll
    for (int off = 32; off > 0; off >>= 1) {
        dot += __shfl_down(dot, off, WAVE);
        s1  += __shfl_down(s1,  off, WAVE);
        s2  += __shfl_down(s2,  off, WAVE);
    }

    __shared__ float sl[WAVES_PER_BLOCK];
    if (lane == 0) {
        float loss = 0.0f;
        if (row < B) {
            float cosv = dot / (sqrtf(s1) * sqrtf(s2));
            float dist = 0.5f * (1.0f - cosv);
            int t = target[row];
            if (t != 0) {
                loss = 0.5f * dist;
            } else {
                float h = fmaxf(0.0f, 1.0f - sqrtf(dist + 1e-9f));
                loss = 0.5f * h * h;
            }
        }
        sl[wv] = loss;
    }
    __syncthreads();
    if (threadIdx.x == 0) {
        block_partial[blockIdx.x] = (sl[0] + sl[1]) + (sl[2] + sl[3]);
    }
}

__global__ __launch_bounds__(BLOCK) void reduce_mean(
    const float* __restrict__ block_partial,
    float* __restrict__ out,
    int nPartial, int B) {
    // Single block; deterministic fixed-order reduction of 2048 partials.
    float sum = 0.0f;
    for (int i = threadIdx.x; i < nPartial; i += BLOCK) sum += block_partial[i];

    #pragma unroll
    for (int off = 32; off > 0; off >>= 1) sum += __shfl_down(sum, off, WAVE);

    __shared__ float smem[WAVES_PER_BLOCK];
    const int lane = threadIdx.x & 63;
    const int wv   = threadIdx.x >> 6;
    if (lane == 0) smem[wv] = sum;
    __syncthreads();
    if (threadIdx.x == 0) {
        float tot = 0.0f;
        #pragma unroll
        for (int w = 0; w < WAVES_PER_BLOCK; ++w) tot += smem[w];
        out[0] = tot / (float)B;
    }
}

extern "C" void kernel_launch(void* const* d_in, const int* in_sizes, int n_in,
                              void* d_out, int out_size, void* d_ws, size_t ws_size,
                              hipStream_t stream) {
    const float* o1 = (const float*)d_in[0];
    const float* o2 = (const float*)d_in[1];
    const int* tgt = (const int*)d_in[2];

    const int B = in_sizes[2];            // 8192
    const int D = in_sizes[0] / B;        // 4096

    float* block_partial = (float*)d_ws;  // grid floats
    float* out = (float*)d_out;

    const int grid = (B + WAVES_PER_BLOCK - 1) / WAVES_PER_BLOCK;  // 2048
    contrastive_row_loss<<<grid, BLOCK, 0, stream>>>(o1, o2, tgt,
                                                     block_partial, B, D);
    reduce_mean<<<1, BLOCK, 0, stream>>>(block_partial, out, grid, B);
}